// Round 3
// baseline (1614.983 us; speedup 1.0000x reference)
//
#include <hip/hip_runtime.h>
#include <hip/hip_bf16.h>
#include <math.h>

#define N_NODES 50000
#define N_EDGES 800000
#define N_GRAPHS 128
#define ORIG_FEA 92
#define NBR_FEA 41
#define H 64
#define N_CONV 3
#define BN_EPS 1e-5f

typedef float v2f __attribute__((ext_vector_type(2)));

__device__ __forceinline__ float sigmoidf_(float x) {
    return __fdividef(1.f, 1.f + __expf(-x));
}
__device__ __forceinline__ float softplusf_(float x) {
    return fmaxf(x, 0.f) + __logf(1.f + __expf(-fabsf(x)));
}

// ---------------------------------------------------------------------------
// Fold W_emb2 / b_emb2 / biases into per-layer edge-attr matrices, stored
// gate-interleaved: W2c[a][k][2*j+gate] (gate 0 = f, 1 = s), cfs[a][2*j+gate].
// ---------------------------------------------------------------------------
__global__ __launch_bounds__(256) void fold_kernel(
    const float* __restrict__ W_emb2, const float* __restrict__ b_emb2,
    const float* __restrict__ Wf, const float* __restrict__ bf,
    const float* __restrict__ Ws, const float* __restrict__ bs,
    float* __restrict__ W2c, float* __restrict__ cfs) {
    int a = blockIdx.x >> 1, gate = blockIdx.x & 1;
    const float* W = (gate ? Ws : Wf) + a * 192 * H + 128 * H;  // [64][64]
    const float* bias = (gate ? bs : bf) + a * H;
    float* Wout = W2c + a * NBR_FEA * 2 * H;
    float* cout = cfs + a * 2 * H;
    for (int idx = threadIdx.x; idx < NBR_FEA * H; idx += blockDim.x) {
        int k = idx / H, j = idx % H;
        float acc = 0.f;
        for (int m = 0; m < H; ++m) acc += W_emb2[k * H + m] * W[m * H + j];
        Wout[k * 2 * H + 2 * j + gate] = acc;
    }
    for (int j = threadIdx.x; j < H; j += blockDim.x) {
        float acc = bias[j];
        for (int m = 0; m < H; ++m) acc += b_emb2[m] * W[m * H + j];
        cout[2 * j + gate] = acc;
    }
}

// ---------------------------------------------------------------------------
// h = x @ W_emb1 + b_emb1  -> state   (50000 x 92 -> 64)
// ---------------------------------------------------------------------------
__global__ __launch_bounds__(256) void embed_kernel(
    const float* __restrict__ x, const float* __restrict__ W,
    const float* __restrict__ b, float* __restrict__ state) {
    __shared__ float lw[ORIG_FEA * H];  // 23.5 KB
    for (int i = threadIdx.x; i < ORIG_FEA * H; i += blockDim.x) lw[i] = W[i];
    __syncthreads();
    int lane = threadIdx.x & 63;
    int wid = (blockIdx.x * blockDim.x + threadIdx.x) >> 6;
    int nw = (gridDim.x * blockDim.x) >> 6;
    for (int n = wid; n < N_NODES; n += nw) {
        int nu = __builtin_amdgcn_readfirstlane(n);
        const float* xr = x + (size_t)nu * ORIG_FEA;  // uniform base -> scalar loads
        float acc = b[lane];
#pragma unroll
        for (int k = 0; k < ORIG_FEA; ++k) acc += xr[k] * lw[k * H + lane];
        state[(size_t)nu * H + lane] = acc;
    }
}

// ---------------------------------------------------------------------------
// CSR construction (edge_index is constant across layers -> build once/call)
// ---------------------------------------------------------------------------
__global__ __launch_bounds__(256) void hist_kernel(
    const int* __restrict__ ei, int* __restrict__ deg) {
    int e = blockIdx.x * blockDim.x + threadIdx.x;
    if (e < N_EDGES) atomicAdd(&deg[ei[N_EDGES + e]], 1);
}

__global__ __launch_bounds__(256) void scan_kernel(
    const int* __restrict__ deg, int* __restrict__ off, int* __restrict__ cur) {
    __shared__ int part[256];
    const int CH = (N_NODES + 255) / 256;  // 196
    int t = threadIdx.x;
    int lo = t * CH, hi = min(lo + CH, N_NODES);
    int s = 0;
    for (int i = lo; i < hi; ++i) s += deg[i];
    part[t] = s;
    __syncthreads();
    for (int o = 1; o < 256; o <<= 1) {
        int v = (t >= o) ? part[t - o] : 0;
        __syncthreads();
        part[t] += v;
        __syncthreads();
    }
    int run = (t == 0) ? 0 : part[t - 1];
    for (int i = lo; i < hi; ++i) {
        off[i] = run;
        cur[i] = run;
        run += deg[i];
    }
    if (t == 255) off[N_NODES] = run;
}

__global__ __launch_bounds__(256) void scatter_kernel(
    const int* __restrict__ ei, int* __restrict__ cur,
    int* __restrict__ perm, int* __restrict__ src_s) {
    int e = blockIdx.x * blockDim.x + threadIdx.x;
    if (e < N_EDGES) {
        int d = ei[N_EDGES + e];
        int p = atomicAdd(&cur[d], 1);
        perm[p] = e;
        src_s[p] = ei[e];
    }
}

// ---------------------------------------------------------------------------
// node_proj_bn: input transform (BN_{a-1}+ReLU if mode, else identity) fused
// with the 4 per-node projections. Writes NPi/NPj (gate-interleaved) + hres.
// ---------------------------------------------------------------------------
__global__ __launch_bounds__(256) void node_proj_bn_kernel(
    const float* __restrict__ state, const float* __restrict__ stats,
    const float* __restrict__ gamma, const float* __restrict__ beta,
    const float* __restrict__ Wf, const float* __restrict__ Ws,
    float* __restrict__ NPi, float* __restrict__ NPj,
    float* __restrict__ hres, int mode) {
    __shared__ float lw[4 * H * H];  // 64 KB: [Wf_i, Wf_j, Ws_i, Ws_j]
    __shared__ float slot[4][H];
    for (int i = threadIdx.x; i < H * H; i += blockDim.x) {
        lw[i] = Wf[i];
        lw[H * H + i] = Wf[H * H + i];
        lw[2 * H * H + i] = Ws[i];
        lw[3 * H * H + i] = Ws[H * H + i];
    }
    int lane = threadIdx.x & 63;
    int wl = threadIdx.x >> 6;
    float A = 1.f, B = 0.f;
    if (mode) {
        const float inv_n = 1.f / (float)N_NODES;
        float mu = stats[lane] * inv_n;
        float var = stats[H + lane] * inv_n - mu * mu;
        float inv = rsqrtf(var + BN_EPS);
        A = inv * gamma[lane];
        B = beta[lane] - mu * A;
    }
    __syncthreads();
    int wid = (blockIdx.x * blockDim.x + threadIdx.x) >> 6;
    int nw = (gridDim.x * blockDim.x) >> 6;
    for (int n = wid; n < N_NODES; n += nw) {
        float z = state[(size_t)n * H + lane];
        float hn = mode ? fmaxf(z * A + B, 0.f) : z;
        hres[(size_t)n * H + lane] = hn;
        slot[wl][lane] = hn;  // wave-local LDS row for broadcast
        float pf = 0.f, qf = 0.f, ps = 0.f, qs = 0.f;
#pragma unroll
        for (int k = 0; k < H; ++k) {
            float s = slot[wl][k];
            pf += s * lw[k * H + lane];
            qf += s * lw[H * H + k * H + lane];
            ps += s * lw[2 * H * H + k * H + lane];
            qs += s * lw[3 * H * H + k * H + lane];
        }
        v2f pi; pi.x = pf; pi.y = ps;
        v2f pj; pj.x = qf; pj.y = qs;
        *(v2f*)&NPi[(size_t)n * 2 * H + 2 * lane] = pi;
        *(v2f*)&NPj[(size_t)n * 2 * H + 2 * lane] = pj;
    }
}

// ---------------------------------------------------------------------------
// Edge aggregation over CSR, no atomics. Wave per node:
//   acc = hres[n]; for e in bucket: acc += sig(.x)*softplus(.y) of
//   (cfs + NPi[n] + NPj[src] + ea[perm[e]] @ W2c); state[n] = acc.
// Also accumulates BN stats (sum, sum^2) -> one atomic pair per wave.
// W2 pairs pinned in VGPRs: asm "memory" clobber makes reloads illegal.
// ---------------------------------------------------------------------------
__global__ __launch_bounds__(256, 3) void edge_csr_kernel(
    const int* __restrict__ off, const int* __restrict__ perm,
    const int* __restrict__ src_s, const float* __restrict__ ea,
    const float* __restrict__ NPi, const float* __restrict__ NPj,
    const float* __restrict__ W2c, const float* __restrict__ cfs,
    const float* __restrict__ hres, float* __restrict__ state,
    float* __restrict__ stats) {
    int lane = threadIdx.x & 63;
    v2f w[NBR_FEA];
#pragma unroll
    for (int k = 0; k < NBR_FEA; ++k)
        w[k] = *(const v2f*)&W2c[k * 2 * H + 2 * lane];
    v2f c2 = *(const v2f*)&cfs[2 * lane];
#pragma unroll
    for (int k = 0; k < NBR_FEA; ++k)
        asm volatile("" : "+v"(w[k])::"memory");  // force-resident in VGPRs
    asm volatile("" : "+v"(c2)::"memory");
    float s = 0.f, s2 = 0.f;
    int wid = (blockIdx.x * blockDim.x + threadIdx.x) >> 6;
    int nw = (gridDim.x * blockDim.x) >> 6;
    for (int n = wid; n < N_NODES; n += nw) {
        int nu = __builtin_amdgcn_readfirstlane(n);
        float acc = hres[(size_t)nu * H + lane];
        v2f base = c2 + *(const v2f*)&NPi[(size_t)nu * 2 * H + 2 * lane];
        int e0 = off[nu], e1 = off[nu + 1];
        for (int e = e0; e < e1; ++e) {
            int eu = __builtin_amdgcn_readfirstlane(perm[e]);
            int src = __builtin_amdgcn_readfirstlane(src_s[e]);
            v2f a2 = base + *(const v2f*)&NPj[(size_t)src * 2 * H + 2 * lane];
            const float* er = ea + (size_t)eu * NBR_FEA;  // uniform -> scalar loads
#pragma unroll
            for (int k = 0; k < NBR_FEA; ++k) a2 += w[k] * er[k];
            acc += sigmoidf_(a2.x) * softplusf_(a2.y);
        }
        state[(size_t)nu * H + lane] = acc;
        s += acc;
        s2 += acc * acc;
    }
    atomicAdd(&stats[lane], s);
    atomicAdd(&stats[H + lane], s2);
}

// ---------------------------------------------------------------------------
// Pool with fused final BN (no relu): gsum[g] += BN2(state[n]); gcnt[g] += 1
// ---------------------------------------------------------------------------
__global__ __launch_bounds__(256) void pool_bn_kernel(
    const float* __restrict__ state, const float* __restrict__ stats,
    const float* __restrict__ gamma, const float* __restrict__ beta,
    const int* __restrict__ batch, float* __restrict__ gsum,
    float* __restrict__ gcnt) {
    int lane = threadIdx.x & 63;
    const float inv_n = 1.f / (float)N_NODES;
    float mu = stats[lane] * inv_n;
    float var = stats[H + lane] * inv_n - mu * mu;
    float inv = rsqrtf(var + BN_EPS);
    float A = inv * gamma[lane];
    float B = beta[lane] - mu * A;
    int wid = (blockIdx.x * blockDim.x + threadIdx.x) >> 6;
    int nw = (gridDim.x * blockDim.x) >> 6;
    for (int n = wid; n < N_NODES; n += nw) {
        int nu = __builtin_amdgcn_readfirstlane(n);
        int g = batch[nu];
        float v = state[(size_t)nu * H + lane] * A + B;
        atomicAdd(&gsum[(size_t)g * H + lane], v);
        if (lane == 0) atomicAdd(&gcnt[g], 1.f);
    }
}

__global__ __launch_bounds__(64) void mlp_kernel(
    const float* __restrict__ gsum, const float* __restrict__ gcnt,
    const float* __restrict__ W1, const float* __restrict__ b1,
    const float* __restrict__ W2, const float* __restrict__ b2,
    const float* __restrict__ Wo, const float* __restrict__ bo,
    float* __restrict__ out) {
    int g = blockIdx.x;
    int lane = threadIdx.x;
    __shared__ float y[H];
    float cnt = fmaxf(gcnt[g], 1.f);
    y[lane] = gsum[(size_t)g * H + lane] / cnt;
    __syncthreads();
    float acc = b1[lane];
#pragma unroll
    for (int k = 0; k < H; ++k) acc += y[k] * W1[k * H + lane];
    float y1 = softplusf_(acc);
    __syncthreads();
    y[lane] = y1;
    __syncthreads();
    acc = b2[lane];
#pragma unroll
    for (int k = 0; k < H; ++k) acc += y[k] * W2[k * H + lane];
    float y2 = softplusf_(acc);
    float t = y2 * Wo[lane];
#pragma unroll
    for (int o = 32; o > 0; o >>= 1) t += __shfl_down(t, o, 64);
    if (lane == 0) out[g] = t + bo[0];
}

extern "C" void kernel_launch(void* const* d_in, const int* in_sizes, int n_in,
                              void* d_out, int out_size, void* d_ws, size_t ws_size,
                              hipStream_t stream) {
    const float* x = (const float*)d_in[0];
    const float* ea = (const float*)d_in[1];
    const int* ei = (const int*)d_in[2];
    const int* batch = (const int*)d_in[3];
    const float* W_emb1 = (const float*)d_in[4];
    const float* b_emb1 = (const float*)d_in[5];
    const float* W_emb2 = (const float*)d_in[6];
    const float* b_emb2 = (const float*)d_in[7];
    const float* Wf = (const float*)d_in[8];
    const float* bf = (const float*)d_in[9];
    const float* Ws = (const float*)d_in[10];
    const float* bs = (const float*)d_in[11];
    const float* gamma = (const float*)d_in[12];
    const float* beta = (const float*)d_in[13];
    const float* W1 = (const float*)d_in[14];
    const float* b1 = (const float*)d_in[15];
    const float* W2 = (const float*)d_in[16];
    const float* b2 = (const float*)d_in[17];
    const float* Wo = (const float*)d_in[18];
    const float* bo = (const float*)d_in[19];
    float* out = (float*)d_out;

    float* w = (float*)d_ws;
    // ---- zeroed region (memset each call) ----
    float* stats = w;                         // 3*2*H = 384
    float* gsum = stats + 3 * 2 * H;          // 8192
    float* gcnt = gsum + N_GRAPHS * H;        // 128
    int* deg = (int*)(gcnt + N_GRAPHS);       // 50000
    const size_t zero_elems = 3 * 2 * H + N_GRAPHS * H + N_GRAPHS + N_NODES;
    // ---- scratch ----
    int* off = deg + N_NODES;                 // 50001
    int* cur = off + N_NODES + 1;             // 50000
    int* perm = cur + N_NODES;                // 800000
    int* src_s = perm + N_EDGES;              // 800000
    float* W2c = (float*)(src_s + N_EDGES);   // 3*41*128
    float* cfs = W2c + 3 * NBR_FEA * 2 * H;   // 3*128
    float* state = cfs + 3 * 2 * H;           // 3.2M
    float* hres = state + (size_t)N_NODES * H;      // 3.2M
    float* NPi = hres + (size_t)N_NODES * H;        // 6.4M
    float* NPj = NPi + (size_t)N_NODES * 2 * H;     // 6.4M

    hipMemsetAsync(w, 0, zero_elems * sizeof(float), stream);

    fold_kernel<<<6, 256, 0, stream>>>(W_emb2, b_emb2, Wf, bf, Ws, bs, W2c, cfs);
    embed_kernel<<<512, 256, 0, stream>>>(x, W_emb1, b_emb1, state);
    hist_kernel<<<(N_EDGES + 255) / 256, 256, 0, stream>>>(ei, deg);
    scan_kernel<<<1, 256, 0, stream>>>(deg, off, cur);
    scatter_kernel<<<(N_EDGES + 255) / 256, 256, 0, stream>>>(ei, cur, perm, src_s);

    for (int a = 0; a < N_CONV; ++a) {
        node_proj_bn_kernel<<<512, 256, 0, stream>>>(
            state, stats + (a - 1) * 2 * H, gamma + (a - 1) * H, beta + (a - 1) * H,
            Wf + a * 192 * H, Ws + a * 192 * H, NPi, NPj, hres, a > 0 ? 1 : 0);
        edge_csr_kernel<<<2048, 256, 0, stream>>>(
            off, perm, src_s, ea, NPi, NPj, W2c + a * NBR_FEA * 2 * H,
            cfs + a * 2 * H, hres, state, stats + a * 2 * H);
    }

    pool_bn_kernel<<<784, 256, 0, stream>>>(state, stats + 2 * 2 * H,
                                            gamma + 2 * H, beta + 2 * H,
                                            batch, gsum, gcnt);
    mlp_kernel<<<128, 64, 0, stream>>>(gsum, gcnt, W1, b1, W2, b2, Wo, bo, out);
}

// Round 4
// 1564.859 us; speedup vs baseline: 1.0320x; 1.0320x over previous
//
#include <hip/hip_runtime.h>
#include <hip/hip_bf16.h>
#include <math.h>

#define N_NODES 50000
#define N_EDGES 800000
#define N_GRAPHS 128
#define ORIG_FEA 92
#define NBR_FEA 41
#define H 64
#define N_CONV 3
#define BN_EPS 1e-5f
#define GROUP 8

typedef float v2f __attribute__((ext_vector_type(2)));

__device__ __forceinline__ float sigmoidf_(float x) {
    return __fdividef(1.f, 1.f + __expf(-x));
}
__device__ __forceinline__ float softplusf_(float x) {
    return fmaxf(x, 0.f) + __logf(1.f + __expf(-fabsf(x)));
}

// ---------------------------------------------------------------------------
// Fold W_emb2 / b_emb2 / biases into per-layer edge-attr matrices, stored
// gate-interleaved: W2c[a][k][2*j+gate] (gate 0 = f, 1 = s), cfs[a][2*j+gate].
// ---------------------------------------------------------------------------
__global__ __launch_bounds__(256) void fold_kernel(
    const float* __restrict__ W_emb2, const float* __restrict__ b_emb2,
    const float* __restrict__ Wf, const float* __restrict__ bf,
    const float* __restrict__ Ws, const float* __restrict__ bs,
    float* __restrict__ W2c, float* __restrict__ cfs) {
    int a = blockIdx.x >> 1, gate = blockIdx.x & 1;
    const float* W = (gate ? Ws : Wf) + a * 192 * H + 128 * H;  // [64][64]
    const float* bias = (gate ? bs : bf) + a * H;
    float* Wout = W2c + a * NBR_FEA * 2 * H;
    float* cout = cfs + a * 2 * H;
    for (int idx = threadIdx.x; idx < NBR_FEA * H; idx += blockDim.x) {
        int k = idx / H, j = idx % H;
        float acc = 0.f;
        for (int m = 0; m < H; ++m) acc += W_emb2[k * H + m] * W[m * H + j];
        Wout[k * 2 * H + 2 * j + gate] = acc;
    }
    for (int j = threadIdx.x; j < H; j += blockDim.x) {
        float acc = bias[j];
        for (int m = 0; m < H; ++m) acc += b_emb2[m] * W[m * H + j];
        cout[2 * j + gate] = acc;
    }
}

// ---------------------------------------------------------------------------
// h = x @ W_emb1 + b_emb1  -> state   (50000 x 92 -> 64)
// ---------------------------------------------------------------------------
__global__ __launch_bounds__(256) void embed_kernel(
    const float* __restrict__ x, const float* __restrict__ W,
    const float* __restrict__ b, float* __restrict__ state) {
    __shared__ float lw[ORIG_FEA * H];  // 23.5 KB
    for (int i = threadIdx.x; i < ORIG_FEA * H; i += blockDim.x) lw[i] = W[i];
    __syncthreads();
    int lane = threadIdx.x & 63;
    int wid = (blockIdx.x * blockDim.x + threadIdx.x) >> 6;
    int nw = (gridDim.x * blockDim.x) >> 6;
    for (int n = wid; n < N_NODES; n += nw) {
        int nu = __builtin_amdgcn_readfirstlane(n);
        const float* xr = x + (size_t)nu * ORIG_FEA;  // uniform base -> scalar loads
        float acc = b[lane];
#pragma unroll
        for (int k = 0; k < ORIG_FEA; ++k) acc += xr[k] * lw[k * H + lane];
        state[(size_t)nu * H + lane] = acc;
    }
}

// ---------------------------------------------------------------------------
// CSR construction (edge_index is constant across layers -> build once/call)
// ---------------------------------------------------------------------------
__global__ __launch_bounds__(256) void hist_kernel(
    const int* __restrict__ ei, int* __restrict__ deg) {
    int e = blockIdx.x * blockDim.x + threadIdx.x;
    if (e < N_EDGES) atomicAdd(&deg[ei[N_EDGES + e]], 1);
}

__global__ __launch_bounds__(256) void scan_kernel(
    const int* __restrict__ deg, int* __restrict__ off, int* __restrict__ cur) {
    __shared__ int part[256];
    const int CH = (N_NODES + 255) / 256;  // 196
    int t = threadIdx.x;
    int lo = t * CH, hi = min(lo + CH, N_NODES);
    int s = 0;
    for (int i = lo; i < hi; ++i) s += deg[i];
    part[t] = s;
    __syncthreads();
    for (int o = 1; o < 256; o <<= 1) {
        int v = (t >= o) ? part[t - o] : 0;
        __syncthreads();
        part[t] += v;
        __syncthreads();
    }
    int run = (t == 0) ? 0 : part[t - 1];
    for (int i = lo; i < hi; ++i) {
        off[i] = run;
        cur[i] = run;
        run += deg[i];
    }
    if (t == 255) off[N_NODES] = run;
}

__global__ __launch_bounds__(256) void scatter_kernel(
    const int* __restrict__ ei, int* __restrict__ cur,
    int* __restrict__ perm, int* __restrict__ src_s) {
    int e = blockIdx.x * blockDim.x + threadIdx.x;
    if (e < N_EDGES) {
        int d = ei[N_EDGES + e];
        int p = atomicAdd(&cur[d], 1);
        perm[p] = e;
        src_s[p] = ei[e];
    }
}

// ---------------------------------------------------------------------------
// node_proj_bn: input transform (BN_{a-1}+ReLU if mode, else identity) fused
// with the 4 per-node projections. Writes NPi/NPj (gate-interleaved).
// ---------------------------------------------------------------------------
__global__ __launch_bounds__(256) void node_proj_bn_kernel(
    const float* __restrict__ state, const float* __restrict__ stats,
    const float* __restrict__ gamma, const float* __restrict__ beta,
    const float* __restrict__ Wf, const float* __restrict__ Ws,
    float* __restrict__ NPi, float* __restrict__ NPj, int mode) {
    __shared__ float lw[4 * H * H];  // 64 KB: [Wf_i, Wf_j, Ws_i, Ws_j]
    __shared__ float slot[4][H];
    for (int i = threadIdx.x; i < H * H; i += blockDim.x) {
        lw[i] = Wf[i];
        lw[H * H + i] = Wf[H * H + i];
        lw[2 * H * H + i] = Ws[i];
        lw[3 * H * H + i] = Ws[H * H + i];
    }
    int lane = threadIdx.x & 63;
    int wl = threadIdx.x >> 6;
    float A = 1.f, B = 0.f;
    if (mode) {
        const float inv_n = 1.f / (float)N_NODES;
        float mu = stats[lane] * inv_n;
        float var = stats[H + lane] * inv_n - mu * mu;
        float inv = rsqrtf(var + BN_EPS);
        A = inv * gamma[lane];
        B = beta[lane] - mu * A;
    }
    __syncthreads();
    int wid = (blockIdx.x * blockDim.x + threadIdx.x) >> 6;
    int nw = (gridDim.x * blockDim.x) >> 6;
    for (int n = wid; n < N_NODES; n += nw) {
        float z = state[(size_t)n * H + lane];
        float hn = mode ? fmaxf(z * A + B, 0.f) : z;
        slot[wl][lane] = hn;  // wave-local LDS row for broadcast
        float pf = 0.f, qf = 0.f, ps = 0.f, qs = 0.f;
#pragma unroll
        for (int k = 0; k < H; ++k) {
            float s = slot[wl][k];
            pf += s * lw[k * H + lane];
            qf += s * lw[H * H + k * H + lane];
            ps += s * lw[2 * H * H + k * H + lane];
            qs += s * lw[3 * H * H + k * H + lane];
        }
        v2f pi; pi.x = pf; pi.y = ps;
        v2f pj; pj.x = qf; pj.y = qs;
        *(v2f*)&NPi[(size_t)n * 2 * H + 2 * lane] = pi;
        *(v2f*)&NPj[(size_t)n * 2 * H + 2 * lane] = pj;
    }
}

// ---------------------------------------------------------------------------
// Edge aggregation over CSR, no atomics. Wave per node, edges in groups of 8.
// Weights live in LDS (guaranteed residency); per group of 8 edges we load
// each weight k-chunk ONCE and apply to all 8 edges -> 8x less weight fetch.
// er rows via wave-uniform scalar loads. Residual h recomputed from state
// (BN_{a-1}+ReLU if mode). Accumulates BN stats (one atomic pair per wave).
// ---------------------------------------------------------------------------
__global__ __launch_bounds__(256) void edge_csr_kernel(
    const int* __restrict__ off, const int* __restrict__ perm,
    const int* __restrict__ src_s, const float* __restrict__ ea,
    const float* __restrict__ NPi, const float* __restrict__ NPj,
    const float* __restrict__ W2c, const float* __restrict__ cfs,
    const float* __restrict__ stats_prev, const float* __restrict__ gamma,
    const float* __restrict__ beta, float* __restrict__ state,
    float* __restrict__ stats_out, int mode) {
    __shared__ float lw[NBR_FEA * 2 * H];  // 21 KB folded edge-attr weights
    for (int i = threadIdx.x; i < NBR_FEA * 2 * H; i += blockDim.x) lw[i] = W2c[i];
    __syncthreads();
    int lane = threadIdx.x & 63;
    v2f c2 = *(const v2f*)&cfs[2 * lane];
    float A = 1.f, B = 0.f;
    if (mode) {
        const float inv_n = 1.f / (float)N_NODES;
        float mu = stats_prev[lane] * inv_n;
        float var = stats_prev[H + lane] * inv_n - mu * mu;
        float inv = rsqrtf(var + BN_EPS);
        A = inv * gamma[lane];
        B = beta[lane] - mu * A;
    }
    float s = 0.f, s2 = 0.f;
    int wid = (blockIdx.x * blockDim.x + threadIdx.x) >> 6;
    int nw = (gridDim.x * blockDim.x) >> 6;
    for (int n = wid; n < N_NODES; n += nw) {
        int nu = __builtin_amdgcn_readfirstlane(n);
        float z = state[(size_t)nu * H + lane];
        float acc = mode ? fmaxf(z * A + B, 0.f) : z;  // residual h
        v2f base = c2 + *(const v2f*)&NPi[(size_t)nu * 2 * H + 2 * lane];
        int e0 = __builtin_amdgcn_readfirstlane(off[nu]);
        int e1 = __builtin_amdgcn_readfirstlane(off[nu + 1]);
        for (int e = e0; e < e1; e += GROUP) {
            int cnt = min(e1 - e, GROUP);
            const float* er[GROUP];
            v2f a2[GROUP];
#pragma unroll
            for (int i = 0; i < GROUP; ++i) {
                int ee = e + (i < cnt ? i : 0);
                int su = __builtin_amdgcn_readfirstlane(src_s[ee]);
                int eu = __builtin_amdgcn_readfirstlane(perm[ee]);
                a2[i] = base + *(const v2f*)&NPj[(size_t)su * 2 * H + 2 * lane];
                er[i] = ea + (size_t)eu * NBR_FEA;  // uniform -> scalar loads
            }
#pragma unroll
            for (int kc = 0; kc < 40; kc += 8) {
                v2f wc[8];
#pragma unroll
                for (int t = 0; t < 8; ++t)
                    wc[t] = *(const v2f*)&lw[(kc + t) * 2 * H + 2 * lane];
#pragma unroll
                for (int i = 0; i < GROUP; ++i) {
#pragma unroll
                    for (int t = 0; t < 8; ++t) a2[i] += wc[t] * er[i][kc + t];
                }
            }
            v2f w40 = *(const v2f*)&lw[40 * 2 * H + 2 * lane];
#pragma unroll
            for (int i = 0; i < GROUP; ++i) {
                a2[i] += w40 * er[i][40];
                if (i < cnt) acc += sigmoidf_(a2[i].x) * softplusf_(a2[i].y);
            }
        }
        state[(size_t)nu * H + lane] = acc;
        s += acc;
        s2 += acc * acc;
    }
    atomicAdd(&stats_out[lane], s);
    atomicAdd(&stats_out[H + lane], s2);
}

// ---------------------------------------------------------------------------
// Pool with fused final BN (no relu): gsum[g] += BN2(state[n]); gcnt[g] += 1
// ---------------------------------------------------------------------------
__global__ __launch_bounds__(256) void pool_bn_kernel(
    const float* __restrict__ state, const float* __restrict__ stats,
    const float* __restrict__ gamma, const float* __restrict__ beta,
    const int* __restrict__ batch, float* __restrict__ gsum,
    float* __restrict__ gcnt) {
    int lane = threadIdx.x & 63;
    const float inv_n = 1.f / (float)N_NODES;
    float mu = stats[lane] * inv_n;
    float var = stats[H + lane] * inv_n - mu * mu;
    float inv = rsqrtf(var + BN_EPS);
    float A = inv * gamma[lane];
    float B = beta[lane] - mu * A;
    int wid = (blockIdx.x * blockDim.x + threadIdx.x) >> 6;
    int nw = (gridDim.x * blockDim.x) >> 6;
    for (int n = wid; n < N_NODES; n += nw) {
        int nu = __builtin_amdgcn_readfirstlane(n);
        int g = batch[nu];
        float v = state[(size_t)nu * H + lane] * A + B;
        atomicAdd(&gsum[(size_t)g * H + lane], v);
        if (lane == 0) atomicAdd(&gcnt[g], 1.f);
    }
}

__global__ __launch_bounds__(64) void mlp_kernel(
    const float* __restrict__ gsum, const float* __restrict__ gcnt,
    const float* __restrict__ W1, const float* __restrict__ b1,
    const float* __restrict__ W2, const float* __restrict__ b2,
    const float* __restrict__ Wo, const float* __restrict__ bo,
    float* __restrict__ out) {
    int g = blockIdx.x;
    int lane = threadIdx.x;
    __shared__ float y[H];
    float cnt = fmaxf(gcnt[g], 1.f);
    y[lane] = gsum[(size_t)g * H + lane] / cnt;
    __syncthreads();
    float acc = b1[lane];
#pragma unroll
    for (int k = 0; k < H; ++k) acc += y[k] * W1[k * H + lane];
    float y1 = softplusf_(acc);
    __syncthreads();
    y[lane] = y1;
    __syncthreads();
    acc = b2[lane];
#pragma unroll
    for (int k = 0; k < H; ++k) acc += y[k] * W2[k * H + lane];
    float y2 = softplusf_(acc);
    float t = y2 * Wo[lane];
#pragma unroll
    for (int o = 32; o > 0; o >>= 1) t += __shfl_down(t, o, 64);
    if (lane == 0) out[g] = t + bo[0];
}

extern "C" void kernel_launch(void* const* d_in, const int* in_sizes, int n_in,
                              void* d_out, int out_size, void* d_ws, size_t ws_size,
                              hipStream_t stream) {
    const float* x = (const float*)d_in[0];
    const float* ea = (const float*)d_in[1];
    const int* ei = (const int*)d_in[2];
    const int* batch = (const int*)d_in[3];
    const float* W_emb1 = (const float*)d_in[4];
    const float* b_emb1 = (const float*)d_in[5];
    const float* W_emb2 = (const float*)d_in[6];
    const float* b_emb2 = (const float*)d_in[7];
    const float* Wf = (const float*)d_in[8];
    const float* bf = (const float*)d_in[9];
    const float* Ws = (const float*)d_in[10];
    const float* bs = (const float*)d_in[11];
    const float* gamma = (const float*)d_in[12];
    const float* beta = (const float*)d_in[13];
    const float* W1 = (const float*)d_in[14];
    const float* b1 = (const float*)d_in[15];
    const float* W2 = (const float*)d_in[16];
    const float* b2 = (const float*)d_in[17];
    const float* Wo = (const float*)d_in[18];
    const float* bo = (const float*)d_in[19];
    float* out = (float*)d_out;

    float* w = (float*)d_ws;
    // ---- zeroed region (memset each call) ----
    float* stats = w;                         // 3*2*H = 384
    float* gsum = stats + 3 * 2 * H;          // 8192
    float* gcnt = gsum + N_GRAPHS * H;        // 128
    int* deg = (int*)(gcnt + N_GRAPHS);       // 50000
    const size_t zero_elems = 3 * 2 * H + N_GRAPHS * H + N_GRAPHS + N_NODES;
    // ---- scratch ----
    int* off = deg + N_NODES;                 // 50001
    int* cur = off + N_NODES + 1;             // 50000
    int* perm = cur + N_NODES;                // 800000
    int* src_s = perm + N_EDGES;              // 800000
    float* W2c = (float*)(src_s + N_EDGES);   // 3*41*128
    float* cfs = W2c + 3 * NBR_FEA * 2 * H;   // 3*128
    float* state = cfs + 3 * 2 * H;           // 3.2M
    float* NPi = state + (size_t)N_NODES * H;       // 6.4M
    float* NPj = NPi + (size_t)N_NODES * 2 * H;     // 6.4M

    hipMemsetAsync(w, 0, zero_elems * sizeof(float), stream);

    fold_kernel<<<6, 256, 0, stream>>>(W_emb2, b_emb2, Wf, bf, Ws, bs, W2c, cfs);
    embed_kernel<<<512, 256, 0, stream>>>(x, W_emb1, b_emb1, state);
    hist_kernel<<<(N_EDGES + 255) / 256, 256, 0, stream>>>(ei, deg);
    scan_kernel<<<1, 256, 0, stream>>>(deg, off, cur);
    scatter_kernel<<<(N_EDGES + 255) / 256, 256, 0, stream>>>(ei, cur, perm, src_s);

    for (int a = 0; a < N_CONV; ++a) {
        const float* sp = a > 0 ? stats + (a - 1) * 2 * H : stats;
        const float* gp = a > 0 ? gamma + (a - 1) * H : gamma;
        const float* bp = a > 0 ? beta + (a - 1) * H : beta;
        node_proj_bn_kernel<<<512, 256, 0, stream>>>(
            state, sp, gp, bp, Wf + a * 192 * H, Ws + a * 192 * H,
            NPi, NPj, a > 0 ? 1 : 0);
        edge_csr_kernel<<<2048, 256, 0, stream>>>(
            off, perm, src_s, ea, NPi, NPj, W2c + a * NBR_FEA * 2 * H,
            cfs + a * 2 * H, sp, gp, bp, state, stats + a * 2 * H, a > 0 ? 1 : 0);
    }

    pool_bn_kernel<<<784, 256, 0, stream>>>(state, stats + 2 * 2 * H,
                                            gamma + 2 * H, beta + 2 * H,
                                            batch, gsum, gcnt);
    mlp_kernel<<<128, 64, 0, stream>>>(gsum, gcnt, W1, b1, W2, b2, Wo, bo, out);
}